// Round 16
// baseline (98.929 us; speedup 1.0000x reference)
//
#include <hip/hip_runtime.h>

// Problem constants (from reference setup_inputs)
constexpr int Bb = 32;      // batch
constexpr int Mm = 65536;   // memory slots
constexpr int Ww = 32;      // word width
constexpr int Rr = 4;       // read heads
constexpr int Dd = 256;     // d_in
constexpr int Kk = 8;       // K_NEIGHBORS

constexpr int NB_A = 64;                    // blocks per batch
constexpr int TPB_A = 256;                  // threads per block
constexpr int ROWS_PER_BLOCK = Mm / NB_A;   // 1024
constexpr int TILE_ROWS = 128;              // rows per LDS tile
constexpr int TILES = ROWS_PER_BLOCK / TILE_ROWS;  // 8
constexpr int NBUF = 3;                     // ring buffers (prefetch dist 2)
constexpr int CPL = NB_A * Kk / 64;         // final-merge candidates/lane = 8

// async global->LDS, 16 B per lane; LDS dest = uniform base + lane*16
__device__ __forceinline__ void glds16(const float4* src, float4* dst_lds) {
  __builtin_amdgcn_global_load_lds(
      (const __attribute__((address_space(1))) void*)src,
      (__attribute__((address_space(3))) void*)dst_lds, 16, 0, 0);
}

// ---------------------------------------------------------------------------
// Kernel 1 (fused): [A] per-block rk compute (redundant across the 64 blocks
// of a batch; W_rk is 128 KB -> L2-resident after first generation), then
// [B] R15-validated streaming: ring-3 gload_lds pipeline, prefetch dist 2,
// counted vmcnt, no barriers in the loop, wave-private staging/reads,
// head-split mapping (4 thr/row = {head-pair, chunk-half}, rk hoisted to
// 32 VGPR, 8 ds_read_b128/tile), chunk XOR-swizzle staging. [C] dedup dump
// + wave-w-extracts-head-w block top-8. NO cross-block sync (R13 lesson:
// fences/L2-writebacks cost far more than a dispatch bubble).
// ---------------------------------------------------------------------------
__global__ __launch_bounds__(TPB_A, 2) void topk_partial(
    const float* __restrict__ xi, const float* __restrict__ sparse,
    const float* __restrict__ Wrk, const float* __restrict__ brk,
    float* __restrict__ cand_d, int* __restrict__ cand_i) {
  const int b = blockIdx.y;
  const int tid = threadIdx.x;
  const int lane = tid & 63;
  const int wid = tid >> 6;
  const float INF = __builtin_inff();

  __shared__ float4 xs4[Dd / 4];              // 1 KB (xi[b])
  __shared__ float4 rk4[Rr][8];               // 512 B
  __shared__ float rkn_s[Rr];
  __shared__ float4 tile[NBUF][TILE_ROWS * 8];  // 3 x 16 KB

  // --- [A] rk prologue (R13-validated): rk = xi[b] @ W_rk^T + b_rk ---
  if (tid < Dd / 4)
    xs4[tid] = reinterpret_cast<const float4*>(xi + (size_t)b * Dd)[tid];
  __syncthreads();
  {
    const int i = tid >> 1;   // rw index 0..127
    const int h = tid & 1;    // half of the 256-dim dot
    const float4* wr =
        reinterpret_cast<const float4*>(Wrk) + (size_t)i * 64 + h * 32;
    const float4* xv = xs4 + h * 32;
    float acc = 0.f;
    #pragma unroll 8
    for (int j = 0; j < 32; ++j) {
      float4 w = wr[j], x = xv[j];
      acc = fmaf(w.x, x.x, acc); acc = fmaf(w.y, x.y, acc);
      acc = fmaf(w.z, x.z, acc); acc = fmaf(w.w, x.w, acc);
    }
    acc += __shfl_xor(acc, 1);
    if (h == 0) reinterpret_cast<float*>(rk4)[i] = acc + brk[i];
  }
  __syncthreads();
  if (tid < Rr) {
    const float* p = reinterpret_cast<const float*>(rk4) + tid * 32;
    float s = 0.f;
    #pragma unroll
    for (int j = 0; j < Ww; ++j) s = fmaf(p[j], p[j], s);
    rkn_s[tid] = s;
  }
  __syncthreads();

  // --- [B] streaming (R15-validated) ---
  const int rowBlk = blockIdx.x * ROWS_PER_BLOCK;
  const float4* sb4 =
      reinterpret_cast<const float4*>(sparse) + (size_t)b * Mm * 8;
  // staging source permutation: LDS slot (row, s) receives global chunk
  // s ^ (row&7); groups are 8-row aligned so row&7 == lane>>3 within a gload
  const int perm = ((lane >> 3) * 8) + ((lane & 7) ^ (lane >> 3));

  // head-split thread mapping (rows kept inside this wave's staging window)
  const int pr = lane >> 2;         // row-slot within wave (0..15)
  const int sub = lane & 3;
  const int hg = sub >> 1;          // head group: heads {0,1} or {2,3}
  const int ch = sub & 1;           // chunk half: chunks ch*4 .. ch*4+3
  const int rowL0 = wid * 32 + pr;  // this thread's rows: rowL0, rowL0+16
  const int h0 = hg * 2, h1 = h0 + 1;

  // hoist this thread's rk fragments: 2 heads x 4 chunks = 32 VGPR
  float4 ka[4], kb[4];
  #pragma unroll
  for (int j = 0; j < 4; ++j) {
    ka[j] = rk4[h0][ch * 4 + j];
    kb[j] = rk4[h1][ch * 4 + j];
  }
  const float rknA = rkn_s[h0];
  const float rknB = rkn_s[h1];

  float d8[2][2 * TILES];  // [head-slot][t*2+q]

  // wave wid stages rows [wid*32, wid*32+32) of a tile: 4 x 1 KB gload_lds
  auto STAGE = [&](int buf, int t) {
    const float4* g0 = sb4 + (size_t)(rowBlk + t * TILE_ROWS + wid * 32) * 8;
    float4* l0 = &tile[buf][wid * 32 * 8];
    #pragma unroll
    for (int i = 0; i < 4; ++i) glds16(g0 + i * 64 + perm, l0 + i * 64);
  };

  STAGE(0, 0);
  STAGE(1, 1);
  #pragma unroll
  for (int t = 0; t < TILES; ++t) {
    if (t + 2 < TILES) {
      // this wave's reads of the buffer being overwritten are done (WAR)
      asm volatile("s_waitcnt lgkmcnt(0)" ::: "memory");
      STAGE((t + 2) % NBUF, t + 2);
      asm volatile("s_waitcnt vmcnt(8)" ::: "memory");  // tile t landed
    } else if (t + 1 < TILES) {
      asm volatile("s_waitcnt vmcnt(4)" ::: "memory");  // tile t landed
    } else {
      asm volatile("s_waitcnt vmcnt(0)" ::: "memory");
    }
    #pragma unroll
    for (int q = 0; q < 2; ++q) {
      const int row = rowL0 + q * 16;       // local tile row (wave-private)
      const int rmask = row & 7;
      const float4* tb = &tile[t % NBUF][row * 8];
      float a0 = 0.f, a1 = 0.f, ss = 0.f;
      #pragma unroll
      for (int j = 0; j < 4; ++j) {
        float4 v = tb[(ch * 4 + j) ^ rmask];
        a0 = fmaf(ka[j].x, v.x, a0); a0 = fmaf(ka[j].y, v.y, a0);
        a0 = fmaf(ka[j].z, v.z, a0); a0 = fmaf(ka[j].w, v.w, a0);
        a1 = fmaf(kb[j].x, v.x, a1); a1 = fmaf(kb[j].y, v.y, a1);
        a1 = fmaf(kb[j].z, v.z, a1); a1 = fmaf(kb[j].w, v.w, a1);
        ss = fmaf(v.x, v.x, ss); ss = fmaf(v.y, v.y, ss);
        ss = fmaf(v.z, v.z, ss); ss = fmaf(v.w, v.w, ss);
      }
      // partial d2 over this chunk-half; partner (lane^1) adds the rest
      float pA = fmaf(-2.f, a0, ss);
      float pB = fmaf(-2.f, a1, ss);
      pA += __shfl_xor(pA, 1);
      pB += __shfl_xor(pB, 1);
      d8[0][t * 2 + q] = pA + rknA;
      d8[1][t * 2 + q] = pB + rknB;
    }
  }

  // --- [C] extraction: dedup dump (ch==0 writers cover both head groups)
  //     into tile buf 0 ([4 heads][1024 rows] = 16 KB), wave w -> head w ---
  __syncthreads();  // all waves done streaming (tile bufs free)
  float* dmp = reinterpret_cast<float*>(&tile[0][0]);
  if (ch == 0) {
    #pragma unroll
    for (int t = 0; t < TILES; ++t)
      #pragma unroll
      for (int q = 0; q < 2; ++q) {
        const int rit = rowL0 + q * 16;  // row within tile t
        dmp[h0 * ROWS_PER_BLOCK + t * TILE_ROWS + rit] = d8[0][t * 2 + q];
        dmp[h1 * ROWS_PER_BLOCK + t * TILE_ROWS + rit] = d8[1][t * 2 + q];
      }
  }
  __syncthreads();

  {
    const int r = wid;          // wave w handles head w
    const int e0 = 2 * lane;    // this lane's two rows-within-tile
    float v[2][TILES];
    #pragma unroll
    for (int q = 0; q < 2; ++q)
      #pragma unroll
      for (int s = 0; s < TILES; ++s)
        v[q][s] = dmp[r * ROWS_PER_BLOCK + s * TILE_ROWS + e0 + q];
    const int base = rowBlk + e0;  // row = base + q + s*TILE_ROWS
    size_t o = ((size_t)(b * Rr + r) * NB_A + blockIdx.x) * Kk;
    #pragma unroll
    for (int k = 0; k < Kk; ++k) {
      // per-lane argmin over 16 static slots with global-row tie-break
      float lv = v[0][0];
      int lrow = base;
      #pragma unroll
      for (int q = 0; q < 2; ++q)
        #pragma unroll
        for (int s = 0; s < TILES; ++s) {
          if (q == 0 && s == 0) continue;
          int row = base + q + s * TILE_ROWS;
          if (v[q][s] < lv || (v[q][s] == lv && row < lrow)) {
            lv = v[q][s]; lrow = row;
          }
        }
      // wave butterfly argmin
      float bv = lv;
      int bi = lrow;
      #pragma unroll
      for (int off = 32; off; off >>= 1) {
        float ov = __shfl_xor(bv, off);
        int oi = __shfl_xor(bi, off);
        if (ov < bv || (ov == bv && oi < bi)) { bv = ov; bi = oi; }
      }
      if (lane == 0) { cand_d[o + k] = bv; cand_i[o + k] = bi; }
      // winner slot (value AND row match) -> INF; static indexing
      #pragma unroll
      for (int q = 0; q < 2; ++q)
        #pragma unroll
        for (int s = 0; s < TILES; ++s) {
          bool clr = (v[q][s] == bv) && (base + q + s * TILE_ROWS == bi);
          v[q][s] = clr ? INF : v[q][s];
        }
    }
  }
}

// ---------------------------------------------------------------------------
// Kernel 2: merge 64*8 candidates per (b,r) -> global top-8, weights, gather
// ---------------------------------------------------------------------------
__global__ __launch_bounds__(64) void topk_final(
    const float* __restrict__ sparse, const float* __restrict__ cand_d,
    const int* __restrict__ cand_i, float* __restrict__ out) {
  const int br = blockIdx.x;  // b*4 + r
  const int b = br >> 2;
  const int r = br & 3;
  const int lane = threadIdx.x;  // 64
  const float INF = __builtin_inff();

  float ld[CPL];
  int li[CPL];
  const float* cd = cand_d + (size_t)br * (NB_A * Kk);
  const int* ci = cand_i + (size_t)br * (NB_A * Kk);
  #pragma unroll
  for (int t = 0; t < CPL; ++t) {
    ld[t] = cd[t * 64 + lane];
    li[t] = ci[t * 64 + lane];
  }
  // sort per-lane list ascending (static bubble network)
  #pragma unroll
  for (int i = 0; i < CPL - 1; ++i)
    #pragma unroll
    for (int j = 0; j < CPL - 1 - i; ++j)
      if (ld[j + 1] < ld[j] || (ld[j + 1] == ld[j] && li[j + 1] < li[j])) {
        float td = ld[j]; ld[j] = ld[j + 1]; ld[j + 1] = td;
        int ti = li[j]; li[j] = li[j + 1]; li[j + 1] = ti;
      }

  __shared__ float s_td[Kk];
  __shared__ int s_ti[Kk];
  #pragma unroll
  for (int k = 0; k < Kk; ++k) {
    float v = ld[0];
    int id = li[0];
    #pragma unroll
    for (int off = 32; off; off >>= 1) {  // butterfly: all lanes get the min
      float ov = __shfl_xor(v, off);
      int oi = __shfl_xor(id, off);
      if (ov < v || (ov == v && oi < id)) { v = ov; id = oi; }
    }
    if (lane == 0) { s_td[k] = v; s_ti[k] = id; }
    if (li[0] == id) {  // owner pops head
      #pragma unroll
      for (int j = 0; j < CPL - 1; ++j) { ld[j] = ld[j + 1]; li[j] = li[j + 1]; }
      ld[CPL - 1] = INF;
      li[CPL - 1] = -1;
    }
  }
  __syncthreads();

  // read_weights[r][b][k] = dist_k / dist_7  (dist ascending -> max is last)
  const float dmax = s_td[Kk - 1];
  if (lane < Kk)
    out[(size_t)Rr * Bb * Kk * Ww + ((size_t)r * Bb + b) * Kk + lane] =
        s_td[lane] / dmax;

  // read_vectors[r][b][k][j] = sparse[b][idx_k][j]
  const float* sbase = sparse + (size_t)b * Mm * Ww;
  #pragma unroll
  for (int t = 0; t < (Kk * Ww) / 64; ++t) {
    int e = t * 64 + lane;
    int k = e >> 5;
    int j = e & 31;
    out[(((size_t)r * Bb + b) * Kk + k) * Ww + j] =
        sbase[(size_t)s_ti[k] * Ww + j];
  }
}

// ---------------------------------------------------------------------------
extern "C" void kernel_launch(void* const* d_in, const int* in_sizes, int n_in,
                              void* d_out, int out_size, void* d_ws,
                              size_t ws_size, hipStream_t stream) {
  const float* xi = (const float*)d_in[0];
  const float* sparse = (const float*)d_in[1];
  const float* Wrk = (const float*)d_in[2];
  const float* brk = (const float*)d_in[3];
  float* out = (float*)d_out;

  char* ws = (char*)d_ws;
  float* cand_d = (float*)ws;                      // 32*4*64*8*4 = 262144 B
  int* cand_i = (int*)(ws + 262144);               // 262144 B

  dim3 gridA(NB_A, Bb);
  topk_partial<<<gridA, TPB_A, 0, stream>>>(xi, sparse, Wrk, brk,
                                            cand_d, cand_i);
  topk_final<<<Bb * Rr, 64, 0, stream>>>(sparse, cand_d, cand_i, out);
}

// Round 17
// 90.088 us; speedup vs baseline: 1.0981x; 1.0981x over previous
//
#include <hip/hip_runtime.h>

// Problem constants (from reference setup_inputs)
constexpr int Bb = 32;      // batch
constexpr int Mm = 65536;   // memory slots
constexpr int Ww = 32;      // word width
constexpr int Rr = 4;       // read heads
constexpr int Dd = 256;     // d_in
constexpr int Kk = 8;       // K_NEIGHBORS

constexpr int NB_A = 64;                    // blocks per batch, phase A
constexpr int TPB_A = 256;                  // threads per block
constexpr int ROWS_PER_BLOCK = Mm / NB_A;   // 1024
constexpr int TILE_ROWS = 128;              // rows per LDS tile
constexpr int TILES = ROWS_PER_BLOCK / TILE_ROWS;  // 8
constexpr int NBUF = 3;                     // ring buffers (prefetch dist 2)
constexpr int CPL = NB_A * Kk / 64;         // final-merge candidates/lane = 8

// async global->LDS, 16 B per lane; LDS dest = uniform base + lane*16
__device__ __forceinline__ void glds16(const float4* src, float4* dst_lds) {
  __builtin_amdgcn_global_load_lds(
      (const __attribute__((address_space(1))) void*)src,
      (__attribute__((address_space(3))) void*)dst_lds, 16, 0, 0);
}

// ---------------------------------------------------------------------------
// Kernel 1: read_keys = xi @ W_rk^T + b_rk  (32 x 128), plus ||rk||^2 per (b,r)
// ---------------------------------------------------------------------------
__global__ __launch_bounds__(128) void rk_kernel(
    const float* __restrict__ xi, const float* __restrict__ Wrk,
    const float* __restrict__ brk, float* __restrict__ rk,
    float* __restrict__ rknorm) {
  const int b = blockIdx.x;
  const int tid = threadIdx.x;  // 128 threads = one rw each
  __shared__ float xs[Dd];
  __shared__ float rks[Rr * Ww];
  #pragma unroll
  for (int i = 0; i < Dd; i += 128) xs[i + tid] = xi[b * Dd + i + tid];
  __syncthreads();
  float acc = brk[tid];
  const float4* wr = reinterpret_cast<const float4*>(Wrk + (size_t)tid * Dd);
  #pragma unroll 4
  for (int i = 0; i < Dd / 4; ++i) {
    float4 wv = wr[i];
    acc = fmaf(wv.x, xs[4 * i + 0], acc);
    acc = fmaf(wv.y, xs[4 * i + 1], acc);
    acc = fmaf(wv.z, xs[4 * i + 2], acc);
    acc = fmaf(wv.w, xs[4 * i + 3], acc);
  }
  rk[b * Rr * Ww + tid] = acc;
  rks[tid] = acc;
  __syncthreads();
  if (tid < Rr) {
    float s = 0.f;
    #pragma unroll
    for (int j = 0; j < Ww; ++j) s = fmaf(rks[tid * Ww + j], rks[tid * Ww + j], s);
    rknorm[b * Rr + tid] = s;
  }
}

// ---------------------------------------------------------------------------
// Kernel 2 (= R15 champion + tile-visit STAGGER): ring-3 gload_lds pipeline,
// prefetch dist 2, counted vmcnt, no barriers in the streaming loop,
// wave-private staging/reads, head-split mapping (4 thr/row = {head-pair,
// chunk-half}, rk hoisted to 32 VGPR, 8 ds_read_b128/tile), chunk
// XOR-swizzle staging. NEW: block visits its 8 tiles in rotated order
// t = (t0+v)&7 with t0 = (bx+b)&7, so concurrent blocks' requests are NOT
// congruent mod the HBM channel interleave (breaks the 8 MiB power-of-2
// aliasing of same-x blocks across batches marching in lockstep).
// d8 is indexed by the STATIC visit count v (rule #20); the dump uses the
// runtime actual-tile address (LDS store, fine).
// ---------------------------------------------------------------------------
__global__ __launch_bounds__(TPB_A, 2) void topk_partial(
    const float* __restrict__ sparse, const float* __restrict__ rk,
    const float* __restrict__ rknorm, float* __restrict__ cand_d,
    int* __restrict__ cand_i) {
  const int b = blockIdx.y;
  const int tid = threadIdx.x;
  const int lane = tid & 63;
  const int wid = tid >> 6;
  const float INF = __builtin_inff();

  __shared__ float4 rk4[Rr][8];               // 512 B
  __shared__ float rkn_s[Rr];
  __shared__ float4 tile[NBUF][TILE_ROWS * 8];  // 3 x 16 KB

  if (tid < Rr * Ww) reinterpret_cast<float*>(rk4)[tid] = rk[b * Rr * Ww + tid];
  if (tid < Rr) rkn_s[tid] = rknorm[b * Rr + tid];
  __syncthreads();

  const int rowBlk = blockIdx.x * ROWS_PER_BLOCK;
  const float4* sb4 =
      reinterpret_cast<const float4*>(sparse) + (size_t)b * Mm * 8;
  // staging source permutation: LDS slot (row, s) receives global chunk
  // s ^ (row&7); groups are 8-row aligned so row&7 == lane>>3 within a gload
  const int perm = ((lane >> 3) * 8) + ((lane & 7) ^ (lane >> 3));

  // head-split thread mapping (rows kept inside this wave's staging window)
  const int pr = lane >> 2;         // row-slot within wave (0..15)
  const int sub = lane & 3;
  const int hg = sub >> 1;          // head group: heads {0,1} or {2,3}
  const int ch = sub & 1;           // chunk half: chunks ch*4 .. ch*4+3
  const int rowL0 = wid * 32 + pr;  // this thread's rows: rowL0, rowL0+16
  const int h0 = hg * 2, h1 = h0 + 1;

  // hoist this thread's rk fragments: 2 heads x 4 chunks = 32 VGPR
  float4 ka[4], kb[4];
  #pragma unroll
  for (int j = 0; j < 4; ++j) {
    ka[j] = rk4[h0][ch * 4 + j];
    kb[j] = rk4[h1][ch * 4 + j];
  }
  const float rknA = rkn_s[h0];
  const float rknB = rkn_s[h1];

  float d8[2][2 * TILES];  // [head-slot][v*2+q], v = visit index (STATIC)

  // tile-visit stagger: decorrelate concurrent blocks' address streams
  const int t0 = (blockIdx.x + b) & (TILES - 1);

  // wave wid stages rows [wid*32, wid*32+32) of tile T: 4 x 1 KB gload_lds
  auto STAGE = [&](int buf, int T) {
    const float4* g0 = sb4 + (size_t)(rowBlk + T * TILE_ROWS + wid * 32) * 8;
    float4* l0 = &tile[buf][wid * 32 * 8];
    #pragma unroll
    for (int i = 0; i < 4; ++i) glds16(g0 + i * 64 + perm, l0 + i * 64);
  };

  STAGE(0, t0);
  STAGE(1, (t0 + 1) & (TILES - 1));
  #pragma unroll
  for (int v = 0; v < TILES; ++v) {
    if (v + 2 < TILES) {
      // this wave's reads of the buffer being overwritten are done (WAR)
      asm volatile("s_waitcnt lgkmcnt(0)" ::: "memory");
      STAGE((v + 2) % NBUF, (t0 + v + 2) & (TILES - 1));
      asm volatile("s_waitcnt vmcnt(8)" ::: "memory");  // visit v landed
    } else if (v + 1 < TILES) {
      asm volatile("s_waitcnt vmcnt(4)" ::: "memory");  // visit v landed
    } else {
      asm volatile("s_waitcnt vmcnt(0)" ::: "memory");
    }
    #pragma unroll
    for (int q = 0; q < 2; ++q) {
      const int row = rowL0 + q * 16;       // local tile row (wave-private)
      const int rmask = row & 7;
      const float4* tb = &tile[v % NBUF][row * 8];
      float a0 = 0.f, a1 = 0.f, ss = 0.f;
      #pragma unroll
      for (int j = 0; j < 4; ++j) {
        float4 v4 = tb[(ch * 4 + j) ^ rmask];
        a0 = fmaf(ka[j].x, v4.x, a0); a0 = fmaf(ka[j].y, v4.y, a0);
        a0 = fmaf(ka[j].z, v4.z, a0); a0 = fmaf(ka[j].w, v4.w, a0);
        a1 = fmaf(kb[j].x, v4.x, a1); a1 = fmaf(kb[j].y, v4.y, a1);
        a1 = fmaf(kb[j].z, v4.z, a1); a1 = fmaf(kb[j].w, v4.w, a1);
        ss = fmaf(v4.x, v4.x, ss); ss = fmaf(v4.y, v4.y, ss);
        ss = fmaf(v4.z, v4.z, ss); ss = fmaf(v4.w, v4.w, ss);
      }
      // partial d2 over this chunk-half; partner (lane^1) adds the rest
      float pA = fmaf(-2.f, a0, ss);
      float pB = fmaf(-2.f, a1, ss);
      pA += __shfl_xor(pA, 1);
      pB += __shfl_xor(pB, 1);
      d8[0][v * 2 + q] = pA + rknA;
      d8[1][v * 2 + q] = pB + rknB;
    }
  }

  // --- extraction: dedup dump (ch==0 writers cover both head groups) into
  //     tile buf 0 ([4 heads][1024 rows] = 16 KB), wave w -> head w.
  //     Dump places visit v at its ACTUAL tile T=(t0+v)&7 slot. ---
  __syncthreads();  // all waves done streaming (tile bufs free)
  float* dmp = reinterpret_cast<float*>(&tile[0][0]);
  if (ch == 0) {
    #pragma unroll
    for (int v = 0; v < TILES; ++v) {
      const int T = (t0 + v) & (TILES - 1);
      #pragma unroll
      for (int q = 0; q < 2; ++q) {
        const int rit = rowL0 + q * 16;  // row within tile T
        dmp[h0 * ROWS_PER_BLOCK + T * TILE_ROWS + rit] = d8[0][v * 2 + q];
        dmp[h1 * ROWS_PER_BLOCK + T * TILE_ROWS + rit] = d8[1][v * 2 + q];
      }
    }
  }
  __syncthreads();

  {
    const int r = wid;          // wave w handles head w
    const int e0 = 2 * lane;    // this lane's two rows-within-tile
    float v[2][TILES];
    #pragma unroll
    for (int q = 0; q < 2; ++q)
      #pragma unroll
      for (int s = 0; s < TILES; ++s)
        v[q][s] = dmp[r * ROWS_PER_BLOCK + s * TILE_ROWS + e0 + q];
    const int base = rowBlk + e0;  // row = base + q + s*TILE_ROWS
    size_t o = ((size_t)(b * Rr + r) * NB_A + blockIdx.x) * Kk;
    #pragma unroll
    for (int k = 0; k < Kk; ++k) {
      // per-lane argmin over 16 static slots with global-row tie-break
      float lv = v[0][0];
      int lrow = base;
      #pragma unroll
      for (int q = 0; q < 2; ++q)
        #pragma unroll
        for (int s = 0; s < TILES; ++s) {
          if (q == 0 && s == 0) continue;
          int row = base + q + s * TILE_ROWS;
          if (v[q][s] < lv || (v[q][s] == lv && row < lrow)) {
            lv = v[q][s]; lrow = row;
          }
        }
      // wave butterfly argmin
      float bv = lv;
      int bi = lrow;
      #pragma unroll
      for (int off = 32; off; off >>= 1) {
        float ov = __shfl_xor(bv, off);
        int oi = __shfl_xor(bi, off);
        if (ov < bv || (ov == bv && oi < bi)) { bv = ov; bi = oi; }
      }
      if (lane == 0) { cand_d[o + k] = bv; cand_i[o + k] = bi; }
      // winner slot (value AND row match) -> INF; static indexing
      #pragma unroll
      for (int q = 0; q < 2; ++q)
        #pragma unroll
        for (int s = 0; s < TILES; ++s) {
          bool clr = (v[q][s] == bv) && (base + q + s * TILE_ROWS == bi);
          v[q][s] = clr ? INF : v[q][s];
        }
    }
  }
}

// ---------------------------------------------------------------------------
// Kernel 3: merge 64*8 candidates per (b,r) -> global top-8, weights, gather
// ---------------------------------------------------------------------------
__global__ __launch_bounds__(64) void topk_final(
    const float* __restrict__ sparse, const float* __restrict__ cand_d,
    const int* __restrict__ cand_i, float* __restrict__ out) {
  const int br = blockIdx.x;  // b*4 + r
  const int b = br >> 2;
  const int r = br & 3;
  const int lane = threadIdx.x;  // 64
  const float INF = __builtin_inff();

  float ld[CPL];
  int li[CPL];
  const float* cd = cand_d + (size_t)br * (NB_A * Kk);
  const int* ci = cand_i + (size_t)br * (NB_A * Kk);
  #pragma unroll
  for (int t = 0; t < CPL; ++t) {
    ld[t] = cd[t * 64 + lane];
    li[t] = ci[t * 64 + lane];
  }
  // sort per-lane list ascending (static bubble network)
  #pragma unroll
  for (int i = 0; i < CPL - 1; ++i)
    #pragma unroll
    for (int j = 0; j < CPL - 1 - i; ++j)
      if (ld[j + 1] < ld[j] || (ld[j + 1] == ld[j] && li[j + 1] < li[j])) {
        float td = ld[j]; ld[j] = ld[j + 1]; ld[j + 1] = td;
        int ti = li[j]; li[j] = li[j + 1]; li[j + 1] = ti;
      }

  __shared__ float s_td[Kk];
  __shared__ int s_ti[Kk];
  #pragma unroll
  for (int k = 0; k < Kk; ++k) {
    float v = ld[0];
    int id = li[0];
    #pragma unroll
    for (int off = 32; off; off >>= 1) {  // butterfly: all lanes get the min
      float ov = __shfl_xor(v, off);
      int oi = __shfl_xor(id, off);
      if (ov < v || (ov == v && oi < id)) { v = ov; id = oi; }
    }
    if (lane == 0) { s_td[k] = v; s_ti[k] = id; }
    if (li[0] == id) {  // owner pops head
      #pragma unroll
      for (int j = 0; j < CPL - 1; ++j) { ld[j] = ld[j + 1]; li[j] = li[j + 1]; }
      ld[CPL - 1] = INF;
      li[CPL - 1] = -1;
    }
  }
  __syncthreads();

  // read_weights[r][b][k] = dist_k / dist_7  (dist ascending -> max is last)
  const float dmax = s_td[Kk - 1];
  if (lane < Kk)
    out[(size_t)Rr * Bb * Kk * Ww + ((size_t)r * Bb + b) * Kk + lane] =
        s_td[lane] / dmax;

  // read_vectors[r][b][k][j] = sparse[b][idx_k][j]
  const float* sbase = sparse + (size_t)b * Mm * Ww;
  #pragma unroll
  for (int t = 0; t < (Kk * Ww) / 64; ++t) {
    int e = t * 64 + lane;
    int k = e >> 5;
    int j = e & 31;
    out[(((size_t)r * Bb + b) * Kk + k) * Ww + j] =
        sbase[(size_t)s_ti[k] * Ww + j];
  }
}

// ---------------------------------------------------------------------------
extern "C" void kernel_launch(void* const* d_in, const int* in_sizes, int n_in,
                              void* d_out, int out_size, void* d_ws,
                              size_t ws_size, hipStream_t stream) {
  const float* xi = (const float*)d_in[0];
  const float* sparse = (const float*)d_in[1];
  const float* Wrk = (const float*)d_in[2];
  const float* brk = (const float*)d_in[3];
  float* out = (float*)d_out;

  char* ws = (char*)d_ws;
  float* rk = (float*)ws;                          // 32*128*4      = 16384 B
  float* rknorm = (float*)(ws + 16384);            // 128*4         = 512 B
  float* cand_d = (float*)(ws + 16896);            // 32*4*64*8*4   = 262144 B
  int* cand_i = (int*)(ws + 16896 + 262144);       // 262144 B

  rk_kernel<<<Bb, 128, 0, stream>>>(xi, Wrk, brk, rk, rknorm);
  dim3 gridA(NB_A, Bb);
  topk_partial<<<gridA, TPB_A, 0, stream>>>(sparse, rk, rknorm, cand_d, cand_i);
  topk_final<<<Bb * Rr, 64, 0, stream>>>(sparse, cand_d, cand_i, out);
}